// Round 1
// baseline (213.847 us; speedup 1.0000x reference)
//
#include <hip/hip_runtime.h>
#include <math.h>
#include <float.h>

#define KSEL 30
#define KNRM 8
#define CAP 256

// ---------------- Kernel 1: precompute B (6x6) and q (6) into ws ----------------
// scores[k,l]*sqrt(D) = r_k^T B r_l + (terms const in l, cancel in softmax) + q . r_l
// B = F^T (Wq^T Wk) F,  q = (Wk F)^T (Wq b_f + b_q),  all scaled by 1/sqrt(128).
__global__ __launch_bounds__(256) void k_precompute(
    const float* __restrict__ fc_w, const float* __restrict__ fc_b,
    const float* __restrict__ wq_w, const float* __restrict__ wq_b,
    const float* __restrict__ wk_w, const float* __restrict__ wk_b,
    float* __restrict__ ws)
{
    __shared__ float Gq[128][6];
    __shared__ float Gk[128][6];
    __shared__ float hq[128];
    const int tid = threadIdx.x;

    for (int e = tid; e < 768; e += 256) {
        int r = e / 6, c = e % 6;
        float aq = 0.f, ak = 0.f;
        for (int m = 0; m < 128; ++m) {
            float f = fc_w[m * 6 + c];
            aq += wq_w[r * 128 + m] * f;
            ak += wk_w[r * 128 + m] * f;
        }
        Gq[r][c] = aq;
        Gk[r][c] = ak;
    }
    if (tid < 128) {
        float a = wq_b[tid];
        for (int m = 0; m < 128; ++m) a += wq_w[tid * 128 + m] * fc_b[m];
        hq[tid] = a;
    }
    __syncthreads();

    const float inv_s = 0.0883883476483184f; // 1/sqrt(128)
    if (tid < 36) {
        int a = tid / 6, b = tid % 6;
        float s = 0.f;
        for (int i = 0; i < 128; ++i) s += Gq[i][a] * Gk[i][b];
        ws[tid] = s * inv_s;                 // B row-major: ws[a*6+b]
    }
    if (tid >= 64 && tid < 70) {
        int b = tid - 64;
        float s = 0.f;
        for (int i = 0; i < 128; ++i) s += Gk[i][b] * hq[i];
        ws[36 + b] = s * inv_s;              // q
    }
}

// ---------------- Kernel 2: per-point kNN + reduced attention ----------------
__global__ __launch_bounds__(256, 3) void k_main(
    const float* __restrict__ xw, const float* __restrict__ vp,
    const float* __restrict__ vn, const float* __restrict__ vv,
    const float* __restrict__ ws, float* __restrict__ out, int M)
{
    const int n    = blockIdx.x;
    const int tid  = threadIdx.x;
    const int lane = tid & 63;
    const int wid  = tid >> 6;

    __shared__ int                s_wsum[4];
    __shared__ int                s_cnt;
    __shared__ unsigned long long s_key[CAP];
    __shared__ int                s_sel[KSEL];
    __shared__ float              s_vn[KSEL][3];
    __shared__ float              s_v[KSEL];
    __shared__ float              s_r[KSEL][6];
    __shared__ float              s_t[KSEL][6];
    __shared__ float              s_e[KSEL];
    __shared__ float              s_o[KSEL];
    __shared__ float              s_xn[3];

    const float x0 = xw[n * 3 + 0];
    const float x1 = xw[n * 3 + 1];
    const float x2 = xw[n * 3 + 2];

    // ---- distances: 64 voxels per thread, kept in registers (static indexing) ----
    float d2[64];
#pragma unroll
    for (int j = 0; j < 64; ++j) {
        int vx = tid + (j << 8);
        float dx, dy, dz;
        if (vx < M) {
            dx = __fsub_rn(x0, vp[vx * 3 + 0]);
            dy = __fsub_rn(x1, vp[vx * 3 + 1]);
            dz = __fsub_rn(x2, vp[vx * 3 + 2]);
            // match reference association order, no FMA contraction:
            d2[j] = __fadd_rn(__fadd_rn(__fmul_rn(dx, dx), __fmul_rn(dy, dy)),
                              __fmul_rn(dz, dz));
        } else {
            d2[j] = FLT_MAX;
        }
    }

    // ---- block-wide count of d2 < T ----
    auto blockCount = [&](float T) -> int {
        int c = 0;
#pragma unroll
        for (int j = 0; j < 64; ++j) c += (d2[j] < T) ? 1 : 0;
        for (int off = 32; off > 0; off >>= 1) c += __shfl_down(c, off, 64);
        __syncthreads();
        if (lane == 0) s_wsum[wid] = c;
        __syncthreads();
        int tot = s_wsum[0] + s_wsum[1] + s_wsum[2] + s_wsum[3];
        __syncthreads();
        return tot;
    };
    auto midf = [](float a, float b) -> float {
        unsigned ua = __float_as_uint(a), ub = __float_as_uint(b);
        return __uint_as_float((ua + ub) >> 1);
    };

    // analytic initial radius from Gaussian density: expected count ~ 40
    float xn2 = x0 * x0 + x1 * x1 + x2 * x2;
    float rho = (float)M * 0.063493636f * __expf(-0.5f * xn2);
    float rc  = 30.0f / (rho * 4.1887902f);           // r30^3
    float T   = 1.3f * __powf(rc, 0.66666667f);       // squared-dist threshold

    float lo = 0.f, hi = 0.f;
    bool  have_hi = false;
    int   c = 0;
    for (int it = 0; it < 24; ++it) {
        c = blockCount(T);
        if (c >= KSEL && c <= CAP) break;
        if (c < KSEL) {
            lo = T;
            T  = have_hi ? midf(lo, hi) : T * 2.5f;
        } else {
            hi = T;
            have_hi = true;
            T = midf(lo, hi);
        }
        if (have_hi && (__float_as_uint(hi) - __float_as_uint(lo) <= 1u)) {
            T = hi;
            c = blockCount(T);
            break;
        }
    }

    // ---- compact candidates (< T) into LDS as (dist_bits<<32 | idx) keys ----
    if (tid == 0) s_cnt = 0;
    if (tid < KSEL) s_sel[tid] = 0; // safety init
    __syncthreads();
#pragma unroll
    for (int j = 0; j < 64; ++j) {
        if (d2[j] < T) {
            int p = atomicAdd(&s_cnt, 1);
            if (p < CAP) {
                s_key[p] = ((unsigned long long)__float_as_uint(d2[j]) << 32) |
                           (unsigned)(tid + (j << 8));
            }
        }
    }
    __syncthreads();
    int nc = s_cnt < CAP ? s_cnt : CAP;

    // ---- exact top-30 by rank (keys distinct => unique ranks; idx tiebreak = lax.top_k) ----
    if (tid < nc) {
        unsigned long long me = s_key[tid];
        int rank = 0;
        for (int i = 0; i < nc; ++i) rank += (s_key[i] < me) ? 1 : 0;
        if (rank < KSEL) s_sel[rank] = (int)(me & 0xffffffffull);
    }
    __syncthreads();

    // ---- phase 2: gather features ----
    float r0 = 0.f, r1 = 0.f, r2 = 0.f, r3 = 0.f, r4 = 0.f, r5 = 0.f;
    if (tid < KSEL) {
        int ix = s_sel[tid];
        r0 = __fsub_rn(x0, vp[ix * 3 + 0]);
        r1 = __fsub_rn(x1, vp[ix * 3 + 1]);
        r2 = __fsub_rn(x2, vp[ix * 3 + 2]);
        s_vn[tid][0] = vn[ix * 3 + 0];
        s_vn[tid][1] = vn[ix * 3 + 1];
        s_vn[tid][2] = vn[ix * 3 + 2];
        s_v[tid]     = vv[ix];
        s_r[tid][0] = r0; s_r[tid][1] = r1; s_r[tid][2] = r2;
    }
    __syncthreads();
    if (tid == 0) {
        float a0 = 0.f, a1 = 0.f, a2 = 0.f;
        for (int k = 0; k < KNRM; ++k) {
            a0 += s_vn[k][0]; a1 += s_vn[k][1]; a2 += s_vn[k][2];
        }
        s_xn[0] = a0 * 0.125f; s_xn[1] = a1 * 0.125f; s_xn[2] = a2 * 0.125f;
    }
    __syncthreads();

    if (tid < KSEL) {
        r3 = __fsub_rn(s_xn[0], s_vn[tid][0]);
        r4 = __fsub_rn(s_xn[1], s_vn[tid][1]);
        r5 = __fsub_rn(s_xn[2], s_vn[tid][2]);
        s_r[tid][3] = r3; s_r[tid][4] = r4; s_r[tid][5] = r5;
        float rr[6] = {r0, r1, r2, r3, r4, r5};
        float e = 0.f;
#pragma unroll
        for (int i = 0; i < 6; ++i) e += ws[36 + i] * rr[i];
        s_e[tid] = e;
#pragma unroll
        for (int j = 0; j < 6; ++j) {
            float t = 0.f;
#pragma unroll
            for (int i = 0; i < 6; ++i) t += ws[j * 6 + i] * rr[i];
            s_t[tid][j] = t;
        }
    }
    __syncthreads();

    if (tid < KSEL) {
        float sc[KSEL];
        float mx = -1e30f;
#pragma unroll
        for (int l = 0; l < KSEL; ++l) {
            float s = s_e[l];
            s += r0 * s_t[l][0];
            s += r1 * s_t[l][1];
            s += r2 * s_t[l][2];
            s += r3 * s_t[l][3];
            s += r4 * s_t[l][4];
            s += r5 * s_t[l][5];
            sc[l] = s;
            mx = fmaxf(mx, s);
        }
        float den = 0.f, num = 0.f;
#pragma unroll
        for (int l = 0; l < KSEL; ++l) {
            float w = __expf(sc[l] - mx);
            den += w;
            num += w * s_v[l];
        }
        s_o[tid] = num / den;
    }
    __syncthreads();

    if (tid == 0) {
        float a = 0.f;
        for (int k = 0; k < KSEL; ++k) a += s_o[k];
        out[n] = a * (1.0f / 30.0f);
    }
}

extern "C" void kernel_launch(void* const* d_in, const int* in_sizes, int n_in,
                              void* d_out, int out_size, void* d_ws, size_t ws_size,
                              hipStream_t stream)
{
    const float* xw   = (const float*)d_in[0];
    const float* vp   = (const float*)d_in[1];
    const float* vn   = (const float*)d_in[2];
    const float* vv   = (const float*)d_in[3];
    const float* fc_w = (const float*)d_in[4];
    const float* fc_b = (const float*)d_in[5];
    const float* wq_w = (const float*)d_in[6];
    const float* wq_b = (const float*)d_in[7];
    const float* wk_w = (const float*)d_in[8];
    const float* wk_b = (const float*)d_in[9];
    float* ws = (float*)d_ws;

    int N = in_sizes[0] / 3;
    int M = in_sizes[1] / 3;

    k_precompute<<<1, 256, 0, stream>>>(fc_w, fc_b, wq_w, wq_b, wk_w, wk_b, ws);
    k_main<<<N, 256, 0, stream>>>(xw, vp, vn, vv, ws, (float*)d_out, M);
}